// Round 3
// baseline (576.884 us; speedup 1.0000x reference)
//
#include <hip/hip_runtime.h>
#include <stdint.h>

// WindowedAttn on MI355X (gfx950)
// Pipeline: cast x->bf16 | transpose W_qkv,W_out -> bf16 B^T | GEMM1 (qkv, bf16 out)
//           | flash attention per 128-q tile (S^T / O^T trick) | GEMM2 (fp32 out)
// GEMMs: 256x256 block tile, BK=64, 8 waves (2x4), 8-phase schedule with counted
// vmcnt (T3+T4) + setprio (T5).
// R3 change: B-fragment registers split bE/bO with OVERLAPPING liveness (bO reads
// issued mid-ph1) so no LDS read ever writes a register that a pending MFMA still
// sources at distance-1. WAR interlock between LDS writeback and in-flight MFMA
// source reads was serializing the LDS and matrix pipes (phase = 515+766 cyc,
// MfmaUtil 39%); all frag WAR distances are now >= 2 phases.
// Ring liveness (unchanged from R2):
//   tile t reads A halves {2t,2t+1} (slots (2t+p)%5), B halves {2t,2t+1} ((2t+p)&3)
//   stages: ph0 A(2t+3); ph1 B(2t+3); ph2 A(2t+4); ph3 B(2t+4)
//   wait: vmcnt(4) after ph3's MFMA; tile NT-2 drains vmcnt(0).

typedef unsigned short u16;
typedef unsigned int u32;
typedef __attribute__((ext_vector_type(8))) short bf16x8;   // 8 bf16 = 4 VGPRs
typedef __attribute__((ext_vector_type(4))) float f32x4;

#define QKVN 6144
#define DM 2048

__device__ __forceinline__ u16 f2b(float f) {
  u32 u = __builtin_bit_cast(u32, f);
  u32 r = (u + 0x7fffu + ((u >> 16) & 1u)) >> 16;  // RNE
  return (u16)r;
}

__device__ __forceinline__ void gload_lds16(const void* g, void* l) {
  __builtin_amdgcn_global_load_lds((const __attribute__((address_space(1))) void*)g,
                                   (__attribute__((address_space(3))) void*)l,
                                   16, 0, 0);
}

// ---------------- prep kernels ----------------

__global__ void cast_f32_bf16(const float4* __restrict__ x, uint4* __restrict__ o) {
  int idx = blockIdx.x * 256 + threadIdx.x;   // grid sized exactly: n/8 threads
  float4 a = x[2 * idx];
  float4 b = x[2 * idx + 1];
  uint4 r;
  r.x = (u32)f2b(a.x) | ((u32)f2b(a.y) << 16);
  r.y = (u32)f2b(a.z) | ((u32)f2b(a.w) << 16);
  r.z = (u32)f2b(b.x) | ((u32)f2b(b.y) << 16);
  r.w = (u32)f2b(b.z) | ((u32)f2b(b.w) << 16);
  o[idx] = r;
}

// W (K x N, fp32, row-major) -> Wt (N x K, bf16, row-major)
__global__ void transpose_cast(const float* __restrict__ W, u16* __restrict__ Wt,
                               int K, int N) {
  __shared__ u16 tile[64][65];
  int tx = threadIdx.x & 63;
  int ty = threadIdx.x >> 6;
  int n0 = blockIdx.x * 64;
  int k0 = blockIdx.y * 64;
#pragma unroll
  for (int r = 0; r < 64; r += 4)
    tile[r + ty][tx] = f2b(W[(size_t)(k0 + r + ty) * N + n0 + tx]);
  __syncthreads();
#pragma unroll
  for (int r = 0; r < 64; r += 4)
    Wt[(size_t)(n0 + r + ty) * K + k0 + tx] = tile[tx][r + ty];
}

// ---------------- GEMM: C[M][N] = A[M][K] * Bt[N][K]^T + bias ----------------
// 256x256 tile, BK=64, 512 threads = 8 waves (2 M-halves x 4 N-quarters),
// per wave 8x4 16x16 fragments. 8-phase / 2 K-tiles, counted vmcnt.

template <typename TO>
__global__ __launch_bounds__(512, 2) void gemm_bt256(const u16* __restrict__ A,
                                                     const u16* __restrict__ Bt,
                                                     const float* __restrict__ bias,
                                                     TO* __restrict__ C,
                                                     int M, int N, int K, int nbx) {
  __shared__ u16 As[5 * 8192];   // 80KB: ring of 5 A half-tiles [128][64]
  __shared__ u16 Bs[4 * 8192];   // 64KB: ring of 4 B half-tiles [128][64]
  const int tid = threadIdx.x;
  const int lane = tid & 63;
  const int wave = tid >> 6;    // 0..7
  const int wr = wave >> 2;     // 0..1  M-half
  const int wc = wave & 3;      // 0..3  N-quarter
  const int quad = lane >> 4;
  const int l15 = lane & 15;

  // XCD-aware bijective swizzle (nwg % 8 == 0 for both GEMMs: 768, 256)
  const int nwg = gridDim.x;
  const int id = blockIdx.x;
  const int swz = (id & 7) * (nwg >> 3) + (id >> 3);
  const int bx = swz % nbx;
  const int by = swz / nbx;
  const int m0 = by * 256;
  const int n0 = bx * 256;
  const int NT = K >> 6;        // K-tiles of 64
  const int NH = 2 * NT;        // half-tile count per matrix

  auto stageA = [&](int h, int slot) {
    if (h < NH) {
      const u16* src = A + (size_t)(m0 + ((h & 1) << 7)) * K + ((h >> 1) << 6);
      u16* dst = As + slot * 8192 + (wave << 9);   // + it*4096 below; HW adds lane*16B
#pragma unroll
      for (int it = 0; it < 2; ++it) {
        int s = (it << 9) + (wave << 6) + lane;    // slot position = row*8 + c'
        int row = s >> 3;
        int c = (s & 7) ^ (row & 7);               // pre-swizzled source chunk
        gload_lds16(src + (size_t)row * K + (c << 3), dst + (it << 12));
      }
    }
  };
  auto stageB = [&](int h, int slot) {
    if (h < NH) {
      const u16* src = Bt + (size_t)(n0 + ((h & 1) << 7)) * K + ((h >> 1) << 6);
      u16* dst = Bs + slot * 8192 + (wave << 9);
#pragma unroll
      for (int it = 0; it < 2; ++it) {
        int s = (it << 9) + (wave << 6) + lane;
        int row = s >> 3;
        int c = (s & 7) ^ (row & 7);
        gload_lds16(src + (size_t)row * K + (c << 3), dst + (it << 12));
      }
    }
  };

  f32x4 acc[8][4] = {};
  const int axq = l15 & 7;
  const int aro = l15 << 6;                  // row-in-half * 64
  const int c0 = (quad ^ axq) << 3;          // ks=0 chunk byte-offset/2
  const int c1 = ((4 + quad) ^ axq) << 3;    // ks=1

  // prologue: tile0 halves + lo-halves of tile1
  stageA(0, 0); stageB(0, 0);
  stageA(1, 1); stageB(1, 1);
  stageA(2, 2); stageB(2, 2);
  asm volatile("s_waitcnt vmcnt(4)" ::: "memory");  // tile0 landed; A2,B2 in flight
  __builtin_amdgcn_s_barrier();

  int sa = wr;          // (2t+wr)%5    A read slot
  int h3a = 3;          // (2t+3)%5     A stage slot (odd half of t+1)
  int h4a = 4;          // (2t+4)%5     A stage slot (even half of t+2)

  for (int t = 0; t < NT; ++t) {
    const u16* ar = As + sa * 8192 + aro;
    const u16* bp = Bs + (((2 * t + (wc >> 1)) & 3) * 8192) + ((wc & 1) << 12) + aro;
    bf16x8 a0[4], a1[4], bE[4], bO[4];

    // ---- phase 0: ks=0, rows 0-3 ----
#pragma unroll
    for (int j = 0; j < 4; ++j) bE[j] = *(const bf16x8*)(bp + j * 1024 + c0);
#pragma unroll
    for (int i = 0; i < 4; ++i) a0[i] = *(const bf16x8*)(ar + i * 1024 + c0);
    stageA(2 * t + 3, h3a);
    __builtin_amdgcn_s_barrier();
    asm volatile("s_waitcnt lgkmcnt(0)" ::: "memory");
    __builtin_amdgcn_s_setprio(1);
#pragma unroll
    for (int i = 0; i < 4; ++i)
#pragma unroll
      for (int j = 0; j < 4; ++j)
        acc[i][j] = __builtin_amdgcn_mfma_f32_16x16x32_bf16(a0[i], bE[j], acc[i][j], 0, 0, 0);
    __builtin_amdgcn_s_setprio(0);
    __builtin_amdgcn_s_barrier();

    // ---- phase 1: ks=0, rows 4-7 (reuse bE); issue bO (ks=1) reads mid-phase ----
#pragma unroll
    for (int i = 0; i < 4; ++i) a1[i] = *(const bf16x8*)(ar + (i + 4) * 1024 + c0);
    stageB(2 * t + 3, (2 * t + 3) & 3);
    __builtin_amdgcn_s_barrier();
    asm volatile("s_waitcnt lgkmcnt(0)" ::: "memory");
    // bO issued here: overlaps this phase's MFMA on the LDS pipe, forces bE/bO
    // into distinct registers (overlapping liveness), and gives the ds_read a
    // full phase before its lgkmcnt consumer in ph2. Data resident since tile
    // t-1's end barrier -- no race.
#pragma unroll
    for (int j = 0; j < 4; ++j) bO[j] = *(const bf16x8*)(bp + j * 1024 + c1);
    __builtin_amdgcn_s_setprio(1);
#pragma unroll
    for (int i = 0; i < 4; ++i)
#pragma unroll
      for (int j = 0; j < 4; ++j)
        acc[i + 4][j] = __builtin_amdgcn_mfma_f32_16x16x32_bf16(a1[i], bE[j], acc[i + 4][j], 0, 0, 0);
    __builtin_amdgcn_s_setprio(0);
    __builtin_amdgcn_s_barrier();

    // ---- phase 2: ks=1, rows 0-3 (bO already in flight) ----
#pragma unroll
    for (int i = 0; i < 4; ++i) a0[i] = *(const bf16x8*)(ar + i * 1024 + c1);
    stageA(2 * t + 4, h4a);
    __builtin_amdgcn_s_barrier();
    asm volatile("s_waitcnt lgkmcnt(0)" ::: "memory");
    __builtin_amdgcn_s_setprio(1);
#pragma unroll
    for (int i = 0; i < 4; ++i)
#pragma unroll
      for (int j = 0; j < 4; ++j)
        acc[i][j] = __builtin_amdgcn_mfma_f32_16x16x32_bf16(a0[i], bO[j], acc[i][j], 0, 0, 0);
    __builtin_amdgcn_s_setprio(0);
    __builtin_amdgcn_s_barrier();

    // ---- phase 3: ks=1, rows 4-7 ----
#pragma unroll
    for (int i = 0; i < 4; ++i) a1[i] = *(const bf16x8*)(ar + (i + 4) * 1024 + c1);
    stageB(2 * t + 4, (2 * t + 4) & 3);   // slot (2t)&3: B-lo(t) last read in ph2 -> safe
    __builtin_amdgcn_s_barrier();
    asm volatile("s_waitcnt lgkmcnt(0)" ::: "memory");
    __builtin_amdgcn_s_setprio(1);
#pragma unroll
    for (int i = 0; i < 4; ++i)
#pragma unroll
      for (int j = 0; j < 4; ++j)
        acc[i + 4][j] = __builtin_amdgcn_mfma_f32_16x16x32_bf16(a1[i], bO[j], acc[i + 4][j], 0, 0, 0);
    __builtin_amdgcn_s_setprio(0);
    // counted wait AFTER the MFMA cluster; end-barrier propagates residency.
    if (t + 3 <= NT) {
      asm volatile("s_waitcnt vmcnt(4)" ::: "memory");   // halves <= 2t+3 landed
    } else if (t + 2 == NT) {
      asm volatile("s_waitcnt vmcnt(0)" ::: "memory");   // tail: drain for last tile
    }
    __builtin_amdgcn_s_barrier();

    sa += 2; if (sa >= 5) sa -= 5;
    h3a += 2; if (h3a >= 5) h3a -= 5;
    h4a += 2; if (h4a >= 5) h4a -= 5;
  }

  // epilogue: D row=(quad*4+t), col=l15 (m89-verified layout)
#pragma unroll
  for (int j = 0; j < 4; ++j) {
    int col = n0 + wc * 64 + j * 16 + l15;
    float bv = bias[col];
#pragma unroll
    for (int i = 0; i < 8; ++i) {
      int row = m0 + wr * 128 + i * 16 + quad * 4;
#pragma unroll
      for (int tt = 0; tt < 4; ++tt) {
        float v = acc[i][j][tt] + bv;
        if constexpr (sizeof(TO) == 2)
          C[(size_t)(row + tt) * N + col] = (TO)f2b(v);
        else
          C[(size_t)(row + tt) * N + col] = (TO)v;
      }
    }
  }
}

// ---------------- attention ----------------
// One block per (b, h, win, qtile of 128). kk-tiles of 64.
// S^T = K * Q^T  (A-frag: K rows from global; B-frag: Q rows from global)
// O^T += V^T * P^T (A-frag: Vt LDS [d][kk]; B-frag: Ps LDS [q][kk]) -- both XOR-swizzled.

__global__ __launch_bounds__(256, 2) void attn_win(const u16* __restrict__ qkv,
                                                   u16* __restrict__ attn_out) {
  __shared__ u16 Vt[128 * 64];  // [d][kk], chunk ^ (d&7)
  __shared__ u16 Ps[128 * 64];  // [q][kk], chunk ^ (q&7)
  const int tid = threadIdx.x;
  const int lane = tid & 63;
  const int wave = tid >> 6;
  const int quad = lane >> 4;
  const int l15 = lane & 15;
  const int qt = blockIdx.x;        // 0..3
  const int win = blockIdx.y;       // 0..7
  const int b = blockIdx.z >> 4;
  const int h = blockIdx.z & 15;
  const int tokw = b * 4096 + win * 512;
  const int tokq = tokw + qt * 128;
  const float SCALE = 0.08838834764831845f;

  // Q fragments (kept in registers for the whole block)
  bf16x8 qf[2][4];
  {
    const u16* Qb = qkv + (size_t)tokq * QKVN + h * 128;
#pragma unroll
    for (int j = 0; j < 2; ++j) {
      const u16* Qr = Qb + (size_t)(wave * 32 + j * 16 + l15) * QKVN + quad * 8;
#pragma unroll
      for (int ks = 0; ks < 4; ++ks)
        qf[j][ks] = *(const bf16x8*)(Qr + ks * 32);
    }
  }

  f32x4 acc_o[8][2] = {};
  float mrun[2] = {-1e30f, -1e30f};
  float lrun[2] = {0.f, 0.f};

  const int jt_end = 2 * qt + 1;
  for (int jt = 0; jt <= jt_end; ++jt) {
    // ---- stage V^T into LDS (transpose during write, pairwise packed) ----
    {
      const u16* Vb = qkv + (size_t)(tokw + jt * 64) * QKVN + 4096 + h * 128;
#pragma unroll
      for (int it = 0; it < 2; ++it) {
        int task = it * 256 + tid;    // 512 tasks: 16 d-chunks x 32 kk-pairs
        int p = task & 31;
        int dc = task >> 5;
        int kk0 = p * 2;
        const u16* g0 = Vb + (size_t)kk0 * QKVN + dc * 8;
        uint4 r0 = *(const uint4*)g0;
        uint4 r1 = *(const uint4*)(g0 + QKVN);
        const u16* a0 = (const u16*)&r0;
        const u16* a1 = (const u16*)&r1;
        int c = kk0 >> 3;
        int boff = (kk0 & 7) << 1;
#pragma unroll
        for (int j = 0; j < 8; ++j) {
          int d = dc * 8 + j;
          *(u32*)((char*)Vt + d * 128 + ((c ^ (d & 7)) << 4) + boff) =
              (u32)a0[j] | ((u32)a1[j] << 16);
        }
      }
    }

    // ---- S^T = K * Q^T ----
    f32x4 acc_s[4][2] = {};
    {
      const u16* Kb = qkv + (size_t)(tokw + jt * 64) * QKVN + 2048 + h * 128;
      bf16x8 kf[4][4];
#pragma unroll
      for (int i = 0; i < 4; ++i) {
        const u16* Kr = Kb + (size_t)(i * 16 + l15) * QKVN + quad * 8;
#pragma unroll
        for (int ks = 0; ks < 4; ++ks)
          kf[i][ks] = *(const bf16x8*)(Kr + ks * 32);
      }
#pragma unroll
      for (int ks = 0; ks < 4; ++ks)
#pragma unroll
        for (int i = 0; i < 4; ++i)
#pragma unroll
          for (int j = 0; j < 2; ++j)
            acc_s[i][j] = __builtin_amdgcn_mfma_f32_16x16x32_bf16(kf[i][ks], qf[j][ks],
                                                                  acc_s[i][j], 0, 0, 0);
    }

    // ---- online softmax (per-lane state; q fixed per lane) ----
    const bool need_mask = (jt >= 2 * qt);
#pragma unroll
    for (int j = 0; j < 2; ++j) {
      int ql = wave * 32 + j * 16 + l15;  // q local in 128-tile
      int qg = qt * 128 + ql;             // q in window
      float vmax = -1e30f;
#pragma unroll
      for (int i = 0; i < 4; ++i)
#pragma unroll
        for (int t = 0; t < 4; ++t) {
          float s = acc_s[i][j][t] * SCALE;
          if (need_mask) {
            int kg = jt * 64 + i * 16 + quad * 4 + t;
            if (kg > qg) s = -1e30f;
          }
          acc_s[i][j][t] = s;
          vmax = fmaxf(vmax, s);
        }
      vmax = fmaxf(vmax, __shfl_xor(vmax, 16));
      vmax = fmaxf(vmax, __shfl_xor(vmax, 32));
      float mnew = fmaxf(mrun[j], vmax);
      float alpha = __expf(mrun[j] - mnew);
      mrun[j] = mnew;
      float vsum = 0.f;
#pragma unroll
      for (int i = 0; i < 4; ++i) {
        float p0 = __expf(acc_s[i][j][0] - mnew);
        float p1 = __expf(acc_s[i][j][1] - mnew);
        float p2 = __expf(acc_s[i][j][2] - mnew);
        float p3 = __expf(acc_s[i][j][3] - mnew);
        vsum += (p0 + p1) + (p2 + p3);
        uint2 pk;
        pk.x = (u32)f2b(p0) | ((u32)f2b(p1) << 16);
        pk.y = (u32)f2b(p2) | ((u32)f2b(p3) << 16);
        int kk = i * 16 + quad * 4;
        *(uint2*)((char*)Ps + ql * 128 + (((kk >> 3) ^ (ql & 7)) << 4) + ((kk & 7) << 1)) = pk;
      }
      vsum += __shfl_xor(vsum, 16);
      vsum += __shfl_xor(vsum, 32);
      lrun[j] = lrun[j] * alpha + vsum;
#pragma unroll
      for (int i2 = 0; i2 < 8; ++i2)
#pragma unroll
        for (int t = 0; t < 4; ++t)
          acc_o[i2][j][t] *= alpha;
    }
    __syncthreads();  // Vt staged + Ps written

    // ---- O^T += V^T * P^T ----
#pragma unroll
    for (int ks = 0; ks < 2; ++ks) {
      int kk = ks * 32 + quad * 8;
      int kc = kk >> 3;
      bf16x8 pf[2];
#pragma unroll
      for (int j = 0; j < 2; ++j) {
        int ql = wave * 32 + j * 16 + l15;
        pf[j] = *(const bf16x8*)((char*)Ps + ql * 128 + ((kc ^ (ql & 7)) << 4));
      }
#pragma unroll
      for (int i2 = 0; i2 < 8; ++i2) {
        int d = i2 * 16 + l15;
        bf16x8 vf = *(const bf16x8*)((char*)Vt + d * 128 + ((kc ^ (d & 7)) << 4));
#pragma unroll
        for (int j = 0; j < 2; ++j)
          acc_o[i2][j] = __builtin_amdgcn_mfma_f32_16x16x32_bf16(vf, pf[j], acc_o[i2][j], 0, 0, 0);
      }
    }
    __syncthreads();  // protect Vt/Ps for next jt
  }

  // ---- epilogue: O^T C-layout -> attn_out[tok][h*128+d], 4 contiguous d per store ----
#pragma unroll
  for (int j = 0; j < 2; ++j) {
    float inv = 1.0f / lrun[j];
    int ql = wave * 32 + j * 16 + l15;
    u16* orow = attn_out + (size_t)(tokq + ql) * DM + h * 128;
#pragma unroll
    for (int i2 = 0; i2 < 8; ++i2) {
      int d = i2 * 16 + quad * 4;
      uint2 pk;
      pk.x = (u32)f2b(acc_o[i2][j][0] * inv) | ((u32)f2b(acc_o[i2][j][1] * inv) << 16);
      pk.y = (u32)f2b(acc_o[i2][j][2] * inv) | ((u32)f2b(acc_o[i2][j][3] * inv) << 16);
      *(uint2*)(orow + d) = pk;
    }
  }
}

// ---------------- launch ----------------

extern "C" void kernel_launch(void* const* d_in, const int* in_sizes, int n_in,
                              void* d_out, int out_size, void* d_ws, size_t ws_size,
                              hipStream_t stream) {
  const float* x = (const float*)d_in[0];
  const float* W_qkv = (const float*)d_in[1];
  const float* b_qkv = (const float*)d_in[2];
  const float* W_out = (const float*)d_in[3];
  const float* b_out = (const float*)d_in[4];
  float* out = (float*)d_out;

  char* w = (char*)d_ws;
  u16* xb = (u16*)w;                                   // 32MB [8192][2048]; reused as attn_out
  u16* wqkvT = (u16*)(w + 33554432);                   // 24MB [6144][2048]
  u16* woutT = (u16*)(w + 33554432 + 25165824);        // 8MB  [2048][2048]
  u16* qkv = (u16*)(w + 67108864);                     // 96MB [8192][6144]

  cast_f32_bf16<<<8192, 256, 0, stream>>>((const float4*)x, (uint4*)xb);
  transpose_cast<<<dim3(96, 32), 256, 0, stream>>>(W_qkv, wqkvT, 2048, 6144);
  transpose_cast<<<dim3(32, 32), 256, 0, stream>>>(W_out, woutT, 2048, 2048);
  gemm_bt256<u16><<<768, 512, 0, stream>>>(xb, wqkvT, b_qkv, qkv, 8192, 6144, 2048, 24);
  attn_win<<<dim3(4, 8, 32), 256, 0, stream>>>(qkv, xb);
  gemm_bt256<float><<<256, 512, 0, stream>>>(xb, woutT, b_out, out, 8192, 2048, 2048, 8);
}

// Round 5
// 511.765 us; speedup vs baseline: 1.1272x; 1.1272x over previous
//
#include <hip/hip_runtime.h>
#include <stdint.h>

// WindowedAttn on MI355X (gfx950)
// Pipeline: cast x->bf16 | transpose W_qkv,W_out -> bf16 B^T
//           | GEMM1 -> Q,K into qk[tok][4096] AND V transposed into vt[d][tok]
//           | flash attention per 128-q tile (S^T / O^T trick, V^T staged via
//             global_load_lds double-buffered -- no in-kernel transpose)
//           | GEMM2 (fp32 out)
// GEMMs: round-0 128x128 block tile, BK=64, global_load_lds width=16,
// XOR-swizzled LDS (chunk ^ (row&7)) -> conflict-free ds_read_b128.
// (R1-R3 256x256 8-phase attempts regressed 185->236->260 us; reverted.)
// R4 bench was an infra failure ("container failed twice"); kernel re-audited
// (OOB / deadlock / graph-capture / dbuf race) and resubmitted unchanged.

typedef unsigned short u16;
typedef unsigned int u32;
typedef __attribute__((ext_vector_type(8))) short bf16x8;   // 8 bf16 = 4 VGPRs
typedef __attribute__((ext_vector_type(4))) float f32x4;

#define QKN 4096   // Q,K buffer row stride
#define DM 2048

__device__ __forceinline__ u16 f2b(float f) {
  u32 u = __builtin_bit_cast(u32, f);
  u32 r = (u + 0x7fffu + ((u >> 16) & 1u)) >> 16;  // RNE
  return (u16)r;
}

__device__ __forceinline__ void gload_lds16(const void* g, void* l) {
  __builtin_amdgcn_global_load_lds((const __attribute__((address_space(1))) void*)g,
                                   (__attribute__((address_space(3))) void*)l,
                                   16, 0, 0);
}

// ---------------- prep kernels ----------------

__global__ void cast_f32_bf16(const float4* __restrict__ x, uint4* __restrict__ o) {
  int idx = blockIdx.x * 256 + threadIdx.x;   // grid sized exactly: n/8 threads
  float4 a = x[2 * idx];
  float4 b = x[2 * idx + 1];
  uint4 r;
  r.x = (u32)f2b(a.x) | ((u32)f2b(a.y) << 16);
  r.y = (u32)f2b(a.z) | ((u32)f2b(a.w) << 16);
  r.z = (u32)f2b(b.x) | ((u32)f2b(b.y) << 16);
  r.w = (u32)f2b(b.z) | ((u32)f2b(b.w) << 16);
  o[idx] = r;
}

// W (K x N, fp32, row-major) -> Wt (N x K, bf16, row-major)
__global__ void transpose_cast(const float* __restrict__ W, u16* __restrict__ Wt,
                               int K, int N) {
  __shared__ u16 tile[64][65];
  int tx = threadIdx.x & 63;
  int ty = threadIdx.x >> 6;
  int n0 = blockIdx.x * 64;
  int k0 = blockIdx.y * 64;
#pragma unroll
  for (int r = 0; r < 64; r += 4)
    tile[r + ty][tx] = f2b(W[(size_t)(k0 + r + ty) * N + n0 + tx]);
  __syncthreads();
#pragma unroll
  for (int r = 0; r < 64; r += 4)
    Wt[(size_t)(n0 + r + ty) * K + k0 + tx] = tile[tx][r + ty];
}

// ---------------- GEMM: C[M][N] = A[M][K] * Bt[N][K]^T + bias ----------------
// block 256 = 4 waves (2x2 of 64x64), 4x4 16x16x32 mfma per wave.
// Columns >= vstart are written TRANSPOSED to vt[col-vstart][row] (V^T for attn);
// n0 is 128-aligned so the branch is uniform per block.

template <typename TO>
__global__ __launch_bounds__(256, 3) void gemm_bt(const u16* __restrict__ A,
                                                  const u16* __restrict__ Bt,
                                                  const float* __restrict__ bias,
                                                  TO* __restrict__ C,
                                                  u16* __restrict__ vt,
                                                  int M, int N, int K,
                                                  int crstride, int vstart) {
  __shared__ u16 As[128 * 64];
  __shared__ u16 Bs[128 * 64];
  const int tid = threadIdx.x;
  const int lane = tid & 63;
  const int wave = tid >> 6;
  const int quad = lane >> 4;
  const int l15 = lane & 15;
  const int m0 = blockIdx.y * 128;
  const int n0 = blockIdx.x * 128;
  const int wm = (wave & 1) * 64;
  const int wn = (wave >> 1) * 64;

  f32x4 acc[4][4] = {};

  for (int k0 = 0; k0 < K; k0 += 64) {
    // stage A,B tiles: row = 128B = 8 chunks of 16B; stored chunk c' = c ^ (row&7)
#pragma unroll
    for (int i = 0; i < 4; ++i) {
      int sb = wave * 256 + i * 64;     // wave-uniform slot base
      int s = sb + lane;                // slot = row*8 + c'
      int m = s >> 3;
      int c = (s & 7) ^ (m & 7);        // global chunk to fetch for this slot
      gload_lds16(A + (size_t)(m0 + m) * K + (k0 + c * 8), As + sb * 8);
      gload_lds16(Bt + (size_t)(n0 + m) * K + (k0 + c * 8), Bs + sb * 8);
    }
    __syncthreads();
#pragma unroll
    for (int ks = 0; ks < 2; ++ks) {
      bf16x8 af[4], bf[4];
#pragma unroll
      for (int i = 0; i < 4; ++i) {
        int m = wm + i * 16 + l15;
        af[i] = *(const bf16x8*)(As + m * 64 + (((ks * 4 + quad) ^ (m & 7)) << 3));
        int n = wn + i * 16 + l15;
        bf[i] = *(const bf16x8*)(Bs + n * 64 + (((ks * 4 + quad) ^ (n & 7)) << 3));
      }
#pragma unroll
      for (int i = 0; i < 4; ++i)
#pragma unroll
        for (int j = 0; j < 4; ++j)
          acc[i][j] = __builtin_amdgcn_mfma_f32_16x16x32_bf16(af[i], bf[j], acc[i][j], 0, 0, 0);
    }
    __syncthreads();
  }

  // epilogue: D row=(quad*4+t), col=l15 (m89-verified)
  if (n0 >= vstart) {
    // V block: write transposed vt[d][token], 4 consecutive tokens packed -> 8B store
#pragma unroll
    for (int j = 0; j < 4; ++j) {
      int col = n0 + wn + j * 16 + l15;
      float bv = bias[col];
      u16* vcol = vt + (size_t)(col - vstart) * 8192;
#pragma unroll
      for (int i = 0; i < 4; ++i) {
        int row = m0 + wm + i * 16 + quad * 4;
        uint2 pk;
        pk.x = (u32)f2b(acc[i][j][0] + bv) | ((u32)f2b(acc[i][j][1] + bv) << 16);
        pk.y = (u32)f2b(acc[i][j][2] + bv) | ((u32)f2b(acc[i][j][3] + bv) << 16);
        *(uint2*)(vcol + row) = pk;
      }
    }
  } else {
#pragma unroll
    for (int j = 0; j < 4; ++j) {
      int col = n0 + wn + j * 16 + l15;
      float bv = bias[col];
#pragma unroll
      for (int i = 0; i < 4; ++i) {
        int row = m0 + wm + i * 16 + quad * 4;
#pragma unroll
        for (int t = 0; t < 4; ++t) {
          float v = acc[i][j][t] + bv;
          if constexpr (sizeof(TO) == 2)
            C[(size_t)(row + t) * crstride + col] = (TO)f2b(v);
          else
            C[(size_t)(row + t) * crstride + col] = (TO)v;
        }
      }
    }
  }
}

// ---------------- attention ----------------
// One block per (b, h, win, qtile of 128). kk-tiles of 64.
// S^T = K * Q^T  (A-frag: K rows from global; B-frag: Q rows from global)
// O^T += V^T * P^T (A-frag: Vs LDS [d][kk] staged from global vt via
// global_load_lds, double-buffered + prefetched one jt ahead; B-frag: Ps LDS
// [q][kk]) -- both XOR-swizzled, conflict-free ds_read_b128.
// Stage-completion: the end-of-iteration __syncthreads carries the compiler's
// full vmcnt drain, so Vs[buf] is complete chip-wide before PV reads it, and
// before any stageV(jt+2) overwrite.

__global__ __launch_bounds__(256, 2) void attn_win(const u16* __restrict__ qk,
                                                   const u16* __restrict__ vt,
                                                   u16* __restrict__ attn_out) {
  __shared__ u16 Vs[2][8192];   // [d=128][kk=64], chunk ^ (d&7), double-buffered
  __shared__ u16 Ps[128 * 64];  // [q][kk], chunk ^ (q&7)
  const int tid = threadIdx.x;
  const int lane = tid & 63;
  const int wave = tid >> 6;
  const int quad = lane >> 4;
  const int l15 = lane & 15;
  const int qt = blockIdx.x;        // 0..3
  const int win = blockIdx.y;       // 0..7
  const int b = blockIdx.z >> 4;
  const int h = blockIdx.z & 15;
  const int tokw = b * 4096 + win * 512;
  const int tokq = tokw + qt * 128;
  const float SCALE = 0.08838834764831845f;

  // stage V^T tile for kk-tile jt into Vs[buf]: rows d=0..127, 8 chunks of 16B,
  // stored chunk c' holds source chunk c'^(d&7) (pre-swizzled source, linear dest)
  auto stageV = [&](int jt, int buf) {
    const u16* vbase = vt + (size_t)(h * 128) * 8192 + (tokw + jt * 64);
    char* dst0 = (char*)Vs[buf] + wave * 1024;
#pragma unroll
    for (int it = 0; it < 4; ++it) {
      int ch = it * 256 + wave * 64 + lane;   // 1024 chunks of 16B
      int row = ch >> 3;
      int c = (ch & 7) ^ (row & 7);
      gload_lds16(vbase + (size_t)row * 8192 + c * 8, dst0 + it * 4096);
    }
  };

  stageV(0, 0);

  // Q fragments (kept in registers for the whole block)
  bf16x8 qf[2][4];
  {
    const u16* Qb = qk + (size_t)tokq * QKN + h * 128;
#pragma unroll
    for (int j = 0; j < 2; ++j) {
      const u16* Qr = Qb + (size_t)(wave * 32 + j * 16 + l15) * QKN + quad * 8;
#pragma unroll
      for (int ks = 0; ks < 4; ++ks)
        qf[j][ks] = *(const bf16x8*)(Qr + ks * 32);
    }
  }

  f32x4 acc_o[8][2] = {};
  float mrun[2] = {-1e30f, -1e30f};
  float lrun[2] = {0.f, 0.f};

  const int jt_end = 2 * qt + 1;
  for (int jt = 0; jt <= jt_end; ++jt) {
    // prefetch next V^T tile into the other buffer (fire-and-forget; drained by
    // the end-of-iteration barrier, visible to all waves there)
    if (jt < jt_end) stageV(jt + 1, (jt + 1) & 1);

    // ---- S^T = K * Q^T ----
    f32x4 acc_s[4][2] = {};
    {
      const u16* Kb = qk + (size_t)(tokw + jt * 64) * QKN + 2048 + h * 128;
      bf16x8 kf[4][4];
#pragma unroll
      for (int i = 0; i < 4; ++i) {
        const u16* Kr = Kb + (size_t)(i * 16 + l15) * QKN + quad * 8;
#pragma unroll
        for (int ks = 0; ks < 4; ++ks)
          kf[i][ks] = *(const bf16x8*)(Kr + ks * 32);
      }
#pragma unroll
      for (int ks = 0; ks < 4; ++ks)
#pragma unroll
        for (int i = 0; i < 4; ++i)
#pragma unroll
          for (int j = 0; j < 2; ++j)
            acc_s[i][j] = __builtin_amdgcn_mfma_f32_16x16x32_bf16(kf[i][ks], qf[j][ks],
                                                                  acc_s[i][j], 0, 0, 0);
    }

    // ---- online softmax (per-lane state; q fixed per lane) ----
    const bool need_mask = (jt >= 2 * qt);
#pragma unroll
    for (int j = 0; j < 2; ++j) {
      int ql = wave * 32 + j * 16 + l15;  // q local in 128-tile
      int qg = qt * 128 + ql;             // q in window
      float vmax = -1e30f;
#pragma unroll
      for (int i = 0; i < 4; ++i)
#pragma unroll
        for (int t = 0; t < 4; ++t) {
          float s = acc_s[i][j][t] * SCALE;
          if (need_mask) {
            int kg = jt * 64 + i * 16 + quad * 4 + t;
            if (kg > qg) s = -1e30f;
          }
          acc_s[i][j][t] = s;
          vmax = fmaxf(vmax, s);
        }
      vmax = fmaxf(vmax, __shfl_xor(vmax, 16));
      vmax = fmaxf(vmax, __shfl_xor(vmax, 32));
      // defer-max exact skip: if the tile max doesn't exceed the running max,
      // alpha would be exactly 1 -- skip the rescale (bit-identical result).
      if (vmax > mrun[j]) {
        float alpha = __expf(mrun[j] - vmax);
        mrun[j] = vmax;
        lrun[j] *= alpha;
#pragma unroll
        for (int i2 = 0; i2 < 8; ++i2)
#pragma unroll
          for (int t = 0; t < 4; ++t)
            acc_o[i2][j][t] *= alpha;
      }
      float mnew = mrun[j];
      float vsum = 0.f;
#pragma unroll
      for (int i = 0; i < 4; ++i) {
        float p0 = __expf(acc_s[i][j][0] - mnew);
        float p1 = __expf(acc_s[i][j][1] - mnew);
        float p2 = __expf(acc_s[i][j][2] - mnew);
        float p3 = __expf(acc_s[i][j][3] - mnew);
        vsum += (p0 + p1) + (p2 + p3);
        uint2 pk;
        pk.x = (u32)f2b(p0) | ((u32)f2b(p1) << 16);
        pk.y = (u32)f2b(p2) | ((u32)f2b(p3) << 16);
        int kk = i * 16 + quad * 4;
        *(uint2*)((char*)Ps + ql * 128 + (((kk >> 3) ^ (ql & 7)) << 4) + ((kk & 7) << 1)) = pk;
      }
      vsum += __shfl_xor(vsum, 16);
      vsum += __shfl_xor(vsum, 32);
      lrun[j] += vsum;
    }
    __syncthreads();  // Vs[jt&1] staged (prev iter) + Ps written

    // ---- O^T += V^T * P^T ----
    const u16* Vtile = Vs[jt & 1];
#pragma unroll
    for (int ks = 0; ks < 2; ++ks) {
      int kk = ks * 32 + quad * 8;
      int kc = kk >> 3;
      bf16x8 pf[2];
#pragma unroll
      for (int j = 0; j < 2; ++j) {
        int ql = wave * 32 + j * 16 + l15;
        pf[j] = *(const bf16x8*)((char*)Ps + ql * 128 + ((kc ^ (ql & 7)) << 4));
      }
#pragma unroll
      for (int i2 = 0; i2 < 8; ++i2) {
        int d = i2 * 16 + l15;
        bf16x8 vf = *(const bf16x8*)((char*)Vtile + d * 128 + ((kc ^ (d & 7)) << 4));
#pragma unroll
        for (int j = 0; j < 2; ++j)
          acc_o[i2][j] = __builtin_amdgcn_mfma_f32_16x16x32_bf16(vf, pf[j], acc_o[i2][j], 0, 0, 0);
      }
    }
    __syncthreads();  // protect Vs/Ps for next jt
  }

  // ---- epilogue: O^T C-layout -> attn_out[tok][h*128+d], 4 contiguous d per store ----
#pragma unroll
  for (int j = 0; j < 2; ++j) {
    float inv = 1.0f / lrun[j];
    int ql = wave * 32 + j * 16 + l15;
    u16* orow = attn_out + (size_t)(tokq + ql) * DM + h * 128;
#pragma unroll
    for (int i2 = 0; i2 < 8; ++i2) {
      int d = i2 * 16 + quad * 4;
      uint2 pk;
      pk.x = (u32)f2b(acc_o[i2][j][0] * inv) | ((u32)f2b(acc_o[i2][j][1] * inv) << 16);
      pk.y = (u32)f2b(acc_o[i2][j][2] * inv) | ((u32)f2b(acc_o[i2][j][3] * inv) << 16);
      *(uint2*)(orow + d) = pk;
    }
  }
}

// ---------------- launch ----------------

extern "C" void kernel_launch(void* const* d_in, const int* in_sizes, int n_in,
                              void* d_out, int out_size, void* d_ws, size_t ws_size,
                              hipStream_t stream) {
  const float* x = (const float*)d_in[0];
  const float* W_qkv = (const float*)d_in[1];
  const float* b_qkv = (const float*)d_in[2];
  const float* W_out = (const float*)d_in[3];
  const float* b_out = (const float*)d_in[4];
  float* out = (float*)d_out;

  char* w = (char*)d_ws;
  u16* xb = (u16*)w;                              // 32MB [8192][2048]; reused as attn_out
  u16* wqkvT = (u16*)(w + (32u << 20));           // 24MB [6144][2048]
  u16* woutT = (u16*)(w + (56u << 20));           // 8MB  [2048][2048]
  u16* qk = (u16*)(w + (64u << 20));              // 64MB [8192][4096]  (Q,K)
  u16* vtb = (u16*)(w + (128u << 20));            // 32MB [2048][8192]  (V^T)

  cast_f32_bf16<<<8192, 256, 0, stream>>>((const float4*)x, (uint4*)xb);
  transpose_cast<<<dim3(96, 32), 256, 0, stream>>>(W_qkv, wqkvT, 2048, 6144);
  transpose_cast<<<dim3(32, 32), 256, 0, stream>>>(W_out, woutT, 2048, 2048);
  gemm_bt<u16><<<dim3(48, 64), 256, 0, stream>>>(xb, wqkvT, b_qkv, qk, vtb,
                                                 8192, 6144, 2048, 4096, 4096);
  attn_win<<<dim3(4, 8, 32), 256, 0, stream>>>(qk, vtb, xb);
  gemm_bt<float><<<dim3(16, 64), 256, 0, stream>>>(xb, woutT, b_out, out, vtb,
                                                   8192, 2048, 2048, 2048, 1 << 28);
}